// Round 5
// baseline (253.049 us; speedup 1.0000x reference)
//
#include <hip/hip_runtime.h>
#include <stdint.h>

// Problem: out[m][n] = sum_k x[m][k] * w[n][k] + bias[n]
//   M=256, N=16384, K=4096, w = dequant(2-bit, group=16 along k)
// Round 5: ZERO-SYNC main loop. The MFMA B-fragment is lane-pure w.r.t.
// dequant (lane l needs cols n=l&15, k=(l>>4)*8..+7 = one uint2 + one norm),
// so each wave dequantizes its own B operands in registers: no LDS, no
// barriers in the K loop. 512-thr blocks = 8 waves (4 m-panels x 2 k-halves),
// wave = 64 rows x 32 cols x K/2; grid 512 = 2 blocks/CU = 4 waves/SIMD.
// Dequant redundancy 4x (q2 L2-shared within block); A direct from the
// fragment-ordered workspace (L2/L3-resident, depth-1 reg prefetch); q2/norm
// depth-2 reg prefetch. One __syncthreads at the end for the k-split merge.
#define M_DIM 256
#define N_DIM 16384
#define K_DIM 4096
#define NCH 64    // 32-wide k-chunks per k-half (2048/32)

typedef __bf16 bf16x8 __attribute__((ext_vector_type(8)));
typedef float  f32x4  __attribute__((ext_vector_type(4)));

// fp32 -> bf16 bits, round-nearest-even (finite inputs)
__device__ __forceinline__ uint32_t f2bf(float f) {
  uint32_t u = __float_as_uint(f);
  return (u + 0x7fffu + ((u >> 16) & 1u)) >> 16;
}

// ---------------------------------------------------------------------------
// Kernel 1 (unchanged): x fp32 [256][4096] -> bf16 fragment-chunk order.
// Chunk = (m-block of 16 rows) x (k-chunk of 32): 64 slots x 16B.
// Slot L holds row (L&15), k = (L>>4)*8 .. +7  (MFMA 16x16x32 A-frag order).
// ws uint4 index = (mb_glob*128 + kch)*64 + L.
// ---------------------------------------------------------------------------
__global__ __launch_bounds__(256) void cvt_x_kernel(const float* __restrict__ x,
                                                    uint4* __restrict__ ws) {
  int T = blockIdx.x * 256 + threadIdx.x;       // 0..131071
  int mb_glob = T >> 13;                        // 16 m-blocks
  int r       = T & 8191;
  int kch     = r >> 6;                         // 128 k-chunks
  int L       = r & 63;
  int row = mb_glob * 16 + (L & 15);
  int k   = kch * 32 + (L >> 4) * 8;
  const float* p = x + (size_t)row * K_DIM + k;
  float4 a = *(const float4*)p;
  float4 b = *(const float4*)(p + 4);
  uint4 o;
  o.x = f2bf(a.x) | (f2bf(a.y) << 16);
  o.y = f2bf(a.z) | (f2bf(a.w) << 16);
  o.z = f2bf(b.x) | (f2bf(b.y) << 16);
  o.w = f2bf(b.z) | (f2bf(b.w) << 16);
  ws[T] = o;
}

// ---------------------------------------------------------------------------
// Dequant 8 elems (2 packed q2 words; 4 crumbs in each low byte) of one group.
// Table entries {-n, a-n, 2a-n, 3a-n}, a = n*2/3 -- bit-identical to the
// fmaf+f2bf reference path.  v_perm_b32 picks the bf16 entry per crumb.
// ---------------------------------------------------------------------------
__device__ __forceinline__ uint4 deq8(uint2 q, float nv) {
  float a2 = nv * (2.0f / 3.0f);
  uint32_t tlo = f2bf(-nv) | (f2bf(fmaf(1.0f, a2, -nv)) << 16);
  uint32_t thi = f2bf(fmaf(2.0f, a2, -nv)) | (f2bf(fmaf(3.0f, a2, -nv)) << 16);
  uint32_t s0 = ((q.x & 3u) | ((q.x & 0xCu) << 14)) * 0x0202u + 0x01000100u;
  uint32_t s1 = (((q.x >> 4) & 3u) | ((q.x & 0xC0u) << 10)) * 0x0202u + 0x01000100u;
  uint32_t s2 = ((q.y & 3u) | ((q.y & 0xCu) << 14)) * 0x0202u + 0x01000100u;
  uint32_t s3 = (((q.y >> 4) & 3u) | ((q.y & 0xC0u) << 10)) * 0x0202u + 0x01000100u;
  uint4 r;
  r.x = __builtin_amdgcn_perm(thi, tlo, s0);
  r.y = __builtin_amdgcn_perm(thi, tlo, s1);
  r.z = __builtin_amdgcn_perm(thi, tlo, s2);
  r.w = __builtin_amdgcn_perm(thi, tlo, s3);
  return r;
}

// ---------------------------------------------------------------------------
// Kernel 2: grid (512), 512 threads, 8 waves: wm = w&3 (rows wm*64..+63),
// kh = w>>2 (k-half). Per 32-k chunk: prefetch A(c+1) frags (4x dwordx4,
// ping-pong regs), dequant the wave's own 2 B-frags from q regs (loaded 2
// chunks earlier), reload q(c+2), 8 MFMA. NO barrier, NO LDS in the loop.
// Epilogue: kh partners merge partial sums via 32KB LDS scratch, one barrier.
// ---------------------------------------------------------------------------
__global__ __launch_bounds__(512, 4) void gemm2bit_kernel(
    const uint4*    __restrict__ aws,  // A chunks (see cvt)
    const uint32_t* __restrict__ q2,   // [G][4] packed 2-bit (low byte crumbs)
    const float*    __restrict__ nrm,  // [G] group norms (f32)
    const float*    __restrict__ bias, // [N]
    float*          __restrict__ out)  // [256][16384] fp32
{
  __shared__ uint4 Sc[2048];  // 32 KiB epilogue k-split scratch

  const int tid  = threadIdx.x;
  const int lane = tid & 63;
  const int w    = tid >> 6;    // 0..7
  const int wm   = w & 3;       // m-panel: rows wm*64..+63
  const int kh   = w >> 2;      // k-half: k in kh*2048..+2047
  const int lo4  = lane & 15;
  const int qd   = lane >> 4;
  const int n0   = blockIdx.x * 32;

  // --- pointers ---
  // A frag: chunk (mb = wm*4+s, kch = kh*64+c) -> aws[(mb*128+kch)*64+lane]
  const uint4* pA = aws + (size_t)wm * 32768 + kh * 4096 + lane;
  // B q2: lane l, frag u: n = n0+u*16+lo4; group g = n*256 + kh*128 + 2c + (qd>>1)
  // uint2 at word (g*4 + (qd&1)*2); chunk stride = 8 words. norm at nrm[g].
  const int gb0 = (n0 + lo4) * 256 + kh * 128 + (qd >> 1);
  const int gb1 = (n0 + 16 + lo4) * 256 + kh * 128 + (qd >> 1);
  const uint32_t* pq0 = q2 + (size_t)gb0 * 4 + (qd & 1) * 2;
  const uint32_t* pq1 = q2 + (size_t)gb1 * 4 + (qd & 1) * 2;
  const float*    pn0 = nrm + gb0;
  const float*    pn1 = nrm + gb1;

  f32x4 acc[4][2];
#pragma unroll
  for (int s = 0; s < 4; ++s)
#pragma unroll
    for (int u = 0; u < 2; ++u)
      acc[s][u] = (f32x4){0.f, 0.f, 0.f, 0.f};

  uint4 afE[4], afO[4];
  uint2 qE0, qE1, qO0, qO1;
  float nE0, nE1, nO0, nO1;

  // ---- prologue: A(0); q(0)->E, q(1)->O ----
#pragma unroll
  for (int s = 0; s < 4; ++s) afE[s] = pA[(size_t)s * 8192];
  qE0 = *(const uint2*)pq0;        nE0 = pn0[0];
  qE1 = *(const uint2*)pq1;        nE1 = pn1[0];
  qO0 = *(const uint2*)(pq0 + 8);  nO0 = pn0[2];
  qO1 = *(const uint2*)(pq1 + 8);  nO1 = pn1[2];

  // Body C: prefetch A(C+1)->AFN; dequant q(C) (in regs); reload q(C+2);
  // 8 MFMA on AFC + dequanted B. No sync.
#define GEMM_BODY(C, AFC, AFN, Q0, N0v, Q1, N1v)                                \
  do {                                                                          \
    if ((C) + 1 < NCH) {                                                        \
      _Pragma("unroll")                                                         \
      for (int s = 0; s < 4; ++s)                                               \
        AFN[s] = pA[(size_t)s * 8192 + ((C) + 1) * 64];                         \
    }                                                                           \
    uint4 b0 = deq8(Q0, N0v);                                                   \
    uint4 b1 = deq8(Q1, N1v);                                                   \
    if ((C) + 2 < NCH) {                                                        \
      Q0  = *(const uint2*)(pq0 + ((C) + 2) * 8);                               \
      N0v = pn0[((C) + 2) * 2];                                                 \
      Q1  = *(const uint2*)(pq1 + ((C) + 2) * 8);                               \
      N1v = pn1[((C) + 2) * 2];                                                 \
    }                                                                           \
    bf16x8 bv0 = __builtin_bit_cast(bf16x8, b0);                                \
    bf16x8 bv1 = __builtin_bit_cast(bf16x8, b1);                                \
    _Pragma("unroll")                                                           \
    for (int s = 0; s < 4; ++s) {                                               \
      bf16x8 av = __builtin_bit_cast(bf16x8, AFC[s]);                           \
      acc[s][0] = __builtin_amdgcn_mfma_f32_16x16x32_bf16(av, bv0,              \
                                                          acc[s][0], 0, 0, 0);  \
      acc[s][1] = __builtin_amdgcn_mfma_f32_16x16x32_bf16(av, bv1,              \
                                                          acc[s][1], 0, 0, 0);  \
    }                                                                           \
  } while (0)

  for (int c = 0; c < NCH; c += 2) {
    GEMM_BODY(c,     afE, afO, qE0, nE0, qE1, nE1);
    GEMM_BODY(c + 1, afO, afE, qO0, nO0, qO1, nO1);
  }
#undef GEMM_BODY

  // ---- epilogue: kh=1 shares partials via LDS; kh=0 merges + bias + store.
  // C/D layout: col = lane&15 (n), row = (lane>>4)*4 + reg (m). ----
  if (kh == 1) {
#pragma unroll
    for (int s = 0; s < 4; ++s)
#pragma unroll
      for (int u = 0; u < 2; ++u)
        Sc[((wm * 4 + s) * 2 + u) * 64 + lane] = __builtin_bit_cast(uint4, acc[s][u]);
  }
  __syncthreads();
  if (kh == 0) {
    float bv[2];
#pragma unroll
    for (int u = 0; u < 2; ++u)
      bv[u] = bias[n0 + u * 16 + lo4];
#pragma unroll
    for (int s = 0; s < 4; ++s) {
      int mrow = wm * 64 + s * 16 + qd * 4;
#pragma unroll
      for (int u = 0; u < 2; ++u) {
        f32x4 o = acc[s][u] +
                  __builtin_bit_cast(f32x4, Sc[((wm * 4 + s) * 2 + u) * 64 + lane]);
        int ncol = n0 + u * 16 + lo4;
        float* p = out + (size_t)mrow * N_DIM + ncol;
#pragma unroll
        for (int r = 0; r < 4; ++r)
          p[(size_t)r * N_DIM] = o[r] + bv[u];
      }
    }
  }
}

// ---------------------------------------------------------------------------
extern "C" void kernel_launch(void* const* d_in, const int* in_sizes, int n_in,
                              void* d_out, int out_size, void* d_ws, size_t ws_size,
                              hipStream_t stream) {
  const float*    x    = (const float*)d_in[0];
  const uint32_t* q2   = (const uint32_t*)d_in[1];
  const float*    nm   = (const float*)d_in[2];
  const float*    bias = (const float*)d_in[3];
  float*          out  = (float*)d_out;
  uint4*          aws  = (uint4*)d_ws;   // 2 MiB: x as bf16 fragment chunks

  cvt_x_kernel<<<512, 256, 0, stream>>>(x, aws);
  gemm2bit_kernel<<<dim3(512), 512, 0, stream>>>(aws, q2, nm, bias, out);
}

// Round 6
// 170.047 us; speedup vs baseline: 1.4881x; 1.4881x over previous
//
#include <hip/hip_runtime.h>
#include <stdint.h>

// Problem: out[m][n] = sum_k x[m][k] * w[n][k] + bias[n]
//   M=256, N=16384, K=4096, w = dequant(2-bit, group=16 along k)
// Round 6: round-3 skeleton (BM=128/BN=64, grid (256,2), 8 waves = 4m x 2n,
// A direct-from-workspace, B-only LDS dbuf + XOR swizzle, lgkm-only barrier)
// with the body restructured to amortize/hide the per-body exposed chain:
//  - BK=128 super-bodies: 32 barriers instead of 64; 16 MFMA + 8 ds_read +
//    2 deq8 + 2 ds_write per wave per body.
//  - dequant+ds_write of tile T+1 placed BETWEEN the two MFMA half-clusters
//    (safe: other buffer was consumed before the previous barrier) so the
//    write tail overlaps MFMA instead of sitting before the barrier.
//  - s_setprio(1) around MFMA clusters (role diversity now exists in-body).
//  - pointer-bump induction for A / q2 / norm prefetch streams.
#define M_DIM 256
#define N_DIM 16384
#define K_DIM 4096
#define BN 64
#define BK 128
#define NT2 (K_DIM / BK)   // 32 bodies

typedef __bf16 bf16x8 __attribute__((ext_vector_type(8)));
typedef float  f32x4  __attribute__((ext_vector_type(4)));

// fp32 -> bf16 bits, round-nearest-even (finite inputs)
__device__ __forceinline__ uint32_t f2bf(float f) {
  uint32_t u = __float_as_uint(f);
  return (u + 0x7fffu + ((u >> 16) & 1u)) >> 16;
}

// Barrier that waits ONLY on LDS ops (dbuf ordering) -- global prefetches
// stay in flight across it.
#define LDS_BARRIER() \
  asm volatile("s_waitcnt lgkmcnt(0)\n\ts_barrier" ::: "memory")

// ---------------------------------------------------------------------------
// Kernel 1 (unchanged): x fp32 [256][4096] -> bf16 fragment-chunk order.
// Chunk = (m-block of 16 rows) x (k-chunk of 32): 64 slots x 16B.
// Slot L holds row (L&15), k = (L>>4)*8 .. +7  (MFMA 16x16x32 A-frag order).
// ws uint4 index = (mb_glob*128 + kch)*64 + L.
// ---------------------------------------------------------------------------
__global__ __launch_bounds__(256) void cvt_x_kernel(const float* __restrict__ x,
                                                    uint4* __restrict__ ws) {
  int T = blockIdx.x * 256 + threadIdx.x;       // 0..131071
  int mb_glob = T >> 13;                        // 16 m-blocks
  int r       = T & 8191;
  int kch     = r >> 6;                         // 128 k-chunks
  int L       = r & 63;
  int row = mb_glob * 16 + (L & 15);
  int k   = kch * 32 + (L >> 4) * 8;
  const float* p = x + (size_t)row * K_DIM + k;
  float4 a = *(const float4*)p;
  float4 b = *(const float4*)(p + 4);
  uint4 o;
  o.x = f2bf(a.x) | (f2bf(a.y) << 16);
  o.y = f2bf(a.z) | (f2bf(a.w) << 16);
  o.z = f2bf(b.x) | (f2bf(b.y) << 16);
  o.w = f2bf(b.z) | (f2bf(b.w) << 16);
  ws[T] = o;
}

// ---------------------------------------------------------------------------
// Dequant 8 elems (2 packed q2 words; 4 crumbs in each low byte) of one group.
// Table entries {-n, a-n, 2a-n, 3a-n}, a = n*2/3 -- bit-identical to the
// fmaf+f2bf reference path.  v_perm_b32 picks the bf16 entry per crumb.
// ---------------------------------------------------------------------------
__device__ __forceinline__ uint4 deq8(uint2 q, float nv) {
  float a2 = nv * (2.0f / 3.0f);
  uint32_t tlo = f2bf(-nv) | (f2bf(fmaf(1.0f, a2, -nv)) << 16);
  uint32_t thi = f2bf(fmaf(2.0f, a2, -nv)) | (f2bf(fmaf(3.0f, a2, -nv)) << 16);
  uint32_t s0 = ((q.x & 3u) | ((q.x & 0xCu) << 14)) * 0x0202u + 0x01000100u;
  uint32_t s1 = (((q.x >> 4) & 3u) | ((q.x & 0xC0u) << 10)) * 0x0202u + 0x01000100u;
  uint32_t s2 = ((q.y & 3u) | ((q.y & 0xCu) << 14)) * 0x0202u + 0x01000100u;
  uint32_t s3 = (((q.y >> 4) & 3u) | ((q.y & 0xC0u) << 10)) * 0x0202u + 0x01000100u;
  uint4 r;
  r.x = __builtin_amdgcn_perm(thi, tlo, s0);
  r.y = __builtin_amdgcn_perm(thi, tlo, s1);
  r.z = __builtin_amdgcn_perm(thi, tlo, s2);
  r.w = __builtin_amdgcn_perm(thi, tlo, s3);
  return r;
}

// ---------------------------------------------------------------------------
// Kernel 2: grid (256,2), 512 threads. Wave w: wm=w>>1 (32 m-rows), wn=w&1
// (32 n-cols). Body T (k = T*128..+127): A(T+1) reg-prefetch (8x uint4,
// ping-pong), MFMA c=0,1 | deq+write tile T+1 | MFMA c=2,3, reload q(T+3),
// lgkm-only barrier. B LDS: 16 chunks (c*4+nb) x 64 slots, XOR-swizzled.
// ---------------------------------------------------------------------------
__global__ __launch_bounds__(512, 4) void gemm2bit_kernel(
    const uint4*    __restrict__ aws,  // A chunks (see cvt)
    const uint32_t* __restrict__ q2,   // [G][4] packed 2-bit (low byte crumbs)
    const float*    __restrict__ nrm,  // [G] group norms (f32)
    const float*    __restrict__ bias, // [N]
    float*          __restrict__ out)  // [256][16384] fp32
{
  __shared__ uint4 Bb[2][1024];  // 16 chunks x 64 slots, dbuf = 32 KiB

  const int tid  = threadIdx.x;
  const int lane = tid & 63;
  const int w    = tid >> 6;    // 0..7
  const int wm   = w >> 1;      // 0..3 : rows m0 + wm*32 .. +31
  const int wn   = w & 1;       // 0..1 : cols n0 + wn*32 .. +31
  const int lo4  = lane & 15;
  const int qd   = lane >> 4;
  const int n0   = blockIdx.x * BN;
  const int m0   = blockIdx.y * 128;

  // swizzled read lane (matches write swizzle below)
  const int lrs = lane ^ qd;

  // --- B staging role: two half-groups per thread (k-groups kg and kg+4) ---
  const int nloc = tid >> 3;          // 0..63 n-row within tile
  const int kg   = (tid >> 1) & 3;    // k-group within the low 64-k half
  const int h    = tid & 1;           // half of the group
  const int grow = n0 + nloc;
  const int qd2  = (kg & 1) * 2 + h;
  // chunk for group j: (j>>1)*4 + (nloc>>4); j1 = kg, j2 = kg+4 -> +8 chunks
  const int bs1 = ((kg >> 1) * 4 + (nloc >> 4)) * 64 + qd2 * 16 +
                  ((nloc & 15) ^ qd2);          // phys = logical ^ qd2
  // bs2 = bs1 + 512

  // --- pointers ---
  // A frag source: m-chunk mb = blockIdx.y*8 + wm*2 + s, k-chunk kch.
  const uint4* pA = aws + (size_t)(blockIdx.y * 8 + wm * 2) * 8192 + lane;
  // q2: group g = grow*256 + T*8 + j; uint2 at word g*4 + h*2
  const uint32_t* pq = q2 + ((size_t)grow * 256 + kg) * 4 + h * 2;
  const float*    pn = nrm + (size_t)grow * 256 + kg;

  f32x4 acc[2][2];
#pragma unroll
  for (int s = 0; s < 2; ++s)
#pragma unroll
    for (int u = 0; u < 2; ++u)
      acc[s][u] = (f32x4){0.f, 0.f, 0.f, 0.f};

  uint4 af0[8], af1[8];   // [s*4 + c]
  uint2 qE1, qE2, qO1, qO2;
  float nE1, nE2, nO1, nO2;

  // ---- prologue: A(0) frags; dequant tile 0; prefetch q(1) (E), q(2) (O) ----
#pragma unroll
  for (int s = 0; s < 2; ++s)
#pragma unroll
    for (int c = 0; c < 4; ++c)
      af0[s * 4 + c] = pA[(size_t)s * 8192 + c * 64];
  {
    uint2 x1 = *(const uint2*)pq;
    uint2 x2 = *(const uint2*)(pq + 16);
    float y1 = pn[0], y2 = pn[4];
    qE1 = *(const uint2*)(pq + 32);  qE2 = *(const uint2*)(pq + 48);
    nE1 = pn[8];   nE2 = pn[12];
    qO1 = *(const uint2*)(pq + 64);  qO2 = *(const uint2*)(pq + 80);
    nO1 = pn[16];  nO2 = pn[20];
    Bb[0][bs1]       = deq8(x1, y1);
    Bb[0][bs1 + 512] = deq8(x2, y2);
  }
  LDS_BARRIER();

  const uint4*    pAp = pA + 256;   // A source for tile 1 (+256 uint4/body)
  const uint32_t* pqp = pq + 96;    // q(3) (reloaded at body 0)
  const float*    pnp = pn + 24;

  // one MFMA half-cluster: chunks cbase, cbase+1
#define MFMA_C2(PR, AFC, cbase)                                                 \
  do {                                                                          \
    __builtin_amdgcn_s_setprio(1);                                              \
    _Pragma("unroll")                                                           \
    for (int c = (cbase); c < (cbase) + 2; ++c) {                               \
      bf16x8 bv0 = *(const bf16x8*)&Bb[PR][(c * 4 + wn * 2) * 64 + lrs];        \
      bf16x8 bv1 = *(const bf16x8*)&Bb[PR][(c * 4 + wn * 2 + 1) * 64 + lrs];    \
      _Pragma("unroll")                                                         \
      for (int s = 0; s < 2; ++s) {                                             \
        bf16x8 av = __builtin_bit_cast(bf16x8, AFC[s * 4 + c]);                 \
        acc[s][0] = __builtin_amdgcn_mfma_f32_16x16x32_bf16(av, bv0,            \
                                                            acc[s][0], 0, 0, 0);\
        acc[s][1] = __builtin_amdgcn_mfma_f32_16x16x32_bf16(av, bv1,            \
                                                            acc[s][1], 0, 0, 0);\
      }                                                                         \
    }                                                                           \
    __builtin_amdgcn_s_setprio(0);                                              \
  } while (0)

  // Body T: A(T+1)->AFN; MFMA c01; deq+write tile T+1 into Bb[PR^1];
  // MFMA c23; reload q(T+3); barrier.
#define GEMM_BODY(T, PR, AFC, AFN, Q1, Q2, N1v, N2v)                            \
  do {                                                                          \
    if ((T) + 1 < NT2) {                                                        \
      _Pragma("unroll")                                                         \
      for (int s = 0; s < 2; ++s)                                               \
        _Pragma("unroll")                                                       \
        for (int c = 0; c < 4; ++c)                                             \
          AFN[s * 4 + c] = pAp[(size_t)s * 8192 + c * 64];                      \
    }                                                                           \
    pAp += 256;                                                                 \
    MFMA_C2(PR, AFC, 0);                                                        \
    if ((T) + 1 < NT2) {                                                        \
      Bb[(PR) ^ 1][bs1]       = deq8(Q1, N1v);                                  \
      Bb[(PR) ^ 1][bs1 + 512] = deq8(Q2, N2v);                                  \
    }                                                                           \
    MFMA_C2(PR, AFC, 2);                                                        \
    if ((T) + 3 < NT2) {                                                        \
      Q1  = *(const uint2*)pqp;                                                 \
      Q2  = *(const uint2*)(pqp + 16);                                          \
      N1v = pnp[0];                                                             \
      N2v = pnp[4];                                                             \
    }                                                                           \
    pqp += 32;                                                                  \
    pnp += 8;                                                                   \
    LDS_BARRIER();                                                              \
  } while (0)

  for (int t2 = 0; t2 < NT2; t2 += 2) {
    GEMM_BODY(t2,     0, af0, af1, qE1, qE2, nE1, nE2);
    GEMM_BODY(t2 + 1, 1, af1, af0, qO1, qO2, nO1, nO2);
  }
#undef GEMM_BODY
#undef MFMA_C2

  // ---- epilogue: direct store, C/D layout col=lane&15 (n),
  // row=(lane>>4)*4+reg (m) ----
  float bv[2];
#pragma unroll
  for (int u = 0; u < 2; ++u)
    bv[u] = bias[n0 + wn * 32 + u * 16 + lo4];

#pragma unroll
  for (int s = 0; s < 2; ++s) {
    int mrow = m0 + wm * 32 + s * 16 + qd * 4;
#pragma unroll
    for (int u = 0; u < 2; ++u) {
      int ncol = n0 + wn * 32 + u * 16 + lo4;
      float* p = out + (size_t)mrow * N_DIM + ncol;
#pragma unroll
      for (int r = 0; r < 4; ++r)
        p[(size_t)r * N_DIM] = acc[s][u][r] + bv[u];
    }
  }
}

// ---------------------------------------------------------------------------
extern "C" void kernel_launch(void* const* d_in, const int* in_sizes, int n_in,
                              void* d_out, int out_size, void* d_ws, size_t ws_size,
                              hipStream_t stream) {
  const float*    x    = (const float*)d_in[0];
  const uint32_t* q2   = (const uint32_t*)d_in[1];
  const float*    nm   = (const float*)d_in[2];
  const float*    bias = (const float*)d_in[3];
  float*          out  = (float*)d_out;
  uint4*          aws  = (uint4*)d_ws;   // 2 MiB: x as bf16 fragment chunks

  cvt_x_kernel<<<512, 256, 0, stream>>>(x, aws);
  gemm2bit_kernel<<<dim3(N_DIM / BN, 2), 512, 0, stream>>>(aws, q2, nm, bias, out);
}